// Round 15
// baseline (337.177 us; speedup 1.0000x reference)
//
#include <hip/hip_runtime.h>
#include <hip/hip_bf16.h>
#include <math.h>

typedef __attribute__((ext_vector_type(8))) short bf16x8v;   // 8 bf16 (4 VGPR)
typedef __attribute__((ext_vector_type(4))) float f32x4v;

// ================= shared helpers =================
__device__ __forceinline__ float loadT(const void* p, size_t i, int isbf) {
    if (isbf) return __bfloat162float(((const __hip_bfloat16*)p)[i]);
    return ((const float*)p)[i];
}
__device__ __forceinline__ float quantw(float v, float s) {      // weight VALUE
    return fminf(fmaxf(rintf(v / s), -7.f), 7.f) * s;
}
__device__ __forceinline__ float quantwc(float v, float s) {     // weight CODE
    return fminf(fmaxf(rintf(v / s), -7.f), 7.f);
}
__device__ __forceinline__ float qbias(float v, float den) {     // Int32Bias VALUE
    return rintf(v / den) * den;
}
__device__ __forceinline__ float qrelu(float v, float s) {       // [0,15] VALUE
    return fminf(fmaxf(rintf(fmaxf(v, 0.f) / s), 0.f), 15.f) * s;
}
// code-domain quant-relu: Cint+bias code -> next-layer code
__device__ __forceinline__ float qcode(float Cint, float bcode, float p, float snext) {
    float v = (Cint + bcode) * p;
    return fminf(fmaxf(rintf(fmaxf(v, 0.f) / snext), 0.f), 15.f);
}
__device__ __forceinline__ float bfbits(unsigned u) {            // bf16 bits -> f32
    return __uint_as_float(u << 16);
}

__global__ void k_beacon(float* out, float code) {
    if (threadIdx.x == 0 && blockIdx.x == 0) out[0] = code;
}

// ================= ws layout (floats) =================
// [0..6]=sa0..sa4,sab,sac ; [8..13]=p1,p2,p3,p4,pB,pC ; [15]=isbf
static constexpr int W1C  = 16;     // 756   f32 codes (conv1)
static constexpr int B1C  = 772;    // 28    f32 codes
static constexpr int B2C  = 800;    // 48
static constexpr int B3C  = 848;    // 64
static constexpr int FB1C = 912;    // 128
static constexpr int BBC  = 1040;   // 4
static constexpr int CBC  = 1044;   // 2
static constexpr int FW1B = 1048;   // 36864 floats = 73728 bf16 codes, PAIRED [k/2][128][2]
static constexpr int W2B  = 37912;  // 6144 floats = 12288 bf16 codes [48][256] (k-pad)
static constexpr int W3B  = 44056;  // 6144 floats = 12288 bf16 codes [64][48][2][2]
static constexpr int BWC  = 50200;  // 512  f32 codes
static constexpr int CWC  = 50712;  // 256  f32 codes
static constexpr int PMAXF = 51000; // 35 partial-max slots

// chunks per tensor {w1,w2,w3,fw1,bw,cw} and block-offset prefix
__device__ __constant__ int d_CHK[6]  = { 1, 4, 4, 24, 1, 1 };
__device__ __constant__ int d_POFF[7] = { 0, 1, 5, 9, 33, 34, 35 };

// ============ k_scale: partial maxes (35 blocks) + probe + act scales ============
__global__ __launch_bounds__(256) void k_scale(
    const void* w1, const void* w2, const void* w3, const void* fw1,
    const void* bw, const void* cw,
    const void* s0p, const void* s1p, const void* s2p, const void* s3p,
    const void* s4p, const void* s5p, const void* s6p,
    float* __restrict__ ws)
{
    __shared__ float red[256];
    __shared__ float shisbf;
    const int tid = threadIdx.x, blk = blockIdx.x;
    // wave-parallel storage-format probe (1 load/lane + ballot)
    if (tid < 64) {
        const unsigned short* hb = (const unsigned short*)w1;
        const float a = fabsf(bfbits((unsigned)hb[2 * tid]));
        const unsigned long long bz = __ballot(a == 0.f);
        const unsigned long long bs = __ballot(a > 1e-8f && a < 1e4f);
        if (tid == 0) {
            const int zeros = __popcll(bz), sane = __popcll(bs);
            shisbf = (zeros < 40 && sane >= 40) ? 1.f : 0.f;
        }
    }
    __syncthreads();
    const int isbf = shisbf > 0.5f;
    if (blk == 0) {
        if (tid == 7) ws[15] = shisbf;
        if (tid < 7) {                       // 7 scales read in parallel
            const void* sp[7] = { s0p, s1p, s2p, s3p, s4p, s5p, s6p };
            const void* p = sp[tid];
            float v = *(const float*)p;
            float a = fabsf(v);
            if (!(a > 1e-6f && a < 1e6f)) {
                double d = *(const double*)p;
                double ad = fabs(d);
                if (ad > 1e-6 && ad < 1e6) v = (float)d;
                else v = bfbits((unsigned)(*(const unsigned short*)p));
            }
            ws[tid] = v;
        }
    }
    // tensor/chunk for this block
    int j = 0;
    while (j < 5 && blk >= d_POFF[j + 1]) ++j;
    const int c = blk - d_POFF[j];
    const void* wp[6] = { w1, w2, w3, fw1, bw, cw };
    const int   wn[6] = { 756, 12096, 12288, 73728, 512, 256 };
    const int nw = wn[j];
    const int len = (nw + d_CHK[j] - 1) / d_CHK[j];
    const int i0 = c * len, i1 = min(i0 + len, nw);
    float m = 0.f;
    for (int i = i0 + tid; i < i1; i += 256)
        m = fmaxf(m, fabsf(loadT(wp[j], i, isbf)));
    red[tid] = m; __syncthreads();
    for (int o = 128; o > 0; o >>= 1) {
        if (tid < o) red[tid] = fmaxf(red[tid], red[tid + o]);
        __syncthreads();
    }
    if (tid == 0) ws[PMAXF + blk] = red[0];
}

// ============ k_quant: quantize all weights/biases (34 blocks, short trips) ======
__global__ __launch_bounds__(256) void k_quant(
    const void* w1, const void* b1, const void* w2, const void* b2,
    const void* w3, const void* b3, const void* fw1, const void* fb1,
    const void* bw, const void* bb, const void* cw, const void* cb,
    float* __restrict__ ws)
{
    const int tid = threadIdx.x, blk = blockIdx.x;
    const int isbf = ws[15] > 0.5f;
    auto getscale = [&](int j) {
        float m = 0.f;
        for (int t = d_POFF[j]; t < d_POFF[j + 1]; ++t)
            m = fmaxf(m, ws[PMAXF + t]);
        return m / 7.0f;
    };

    if (blk < 24) {                          // fw1 -> FW1B bf16, paired [kk/2][128][2]
        const float s = getscale(3);
        const int i0 = blk * 3072, i1 = min(i0 + 3072, 73728);
        __hip_bfloat16* dst = (__hip_bfloat16*)(ws + FW1B);
        for (int i = i0 + tid; i < i1; i += 256) {
            const float q = quantwc(loadT(fw1, i, isbf), s);
            const int o = i / 576, f = i % 576;
            const int c = f / 9, fw_ = (f % 9) / 3, fh = f % 3;
            const int kk = c * 9 + fh * 3 + fw_;        // act3 flat k (flatten folded)
            dst[(kk >> 1) * 256 + o * 2 + (kk & 1)] = __float2bfloat16(q);
        }
    } else if (blk < 28) {                   // w2 -> W2B bf16 [48][256]
        const float s = getscale(1);
        const int c = blk - 24;
        const int i0 = c * 3024, i1 = min(i0 + 3024, 12096);
        __hip_bfloat16* dst = (__hip_bfloat16*)(ws + W2B);
        for (int i = i0 + tid; i < i1; i += 256) {
            const float q = quantwc(loadT(w2, i, isbf), s);
            const int n = i / 252, k = i % 252;
            dst[n * 256 + k] = __float2bfloat16(q);
        }
        if (c == 0) {                        // zero-pad k = 252..255
            for (int i = tid; i < 192; i += 256) {
                const int n = i / 4, k = 252 + (i % 4);
                dst[n * 256 + k] = __float2bfloat16(0.f);
            }
        }
    } else if (blk < 32) {                   // w3 -> W3B bf16 [i]
        const float s = getscale(2);
        const int c = blk - 28;
        const int i0 = c * 3072, i1 = min(i0 + 3072, 12288);
        __hip_bfloat16* dst = (__hip_bfloat16*)(ws + W3B);
        for (int i = i0 + tid; i < i1; i += 256)
            dst[i] = __float2bfloat16(quantwc(loadT(w3, i, isbf), s));
    } else if (blk == 32) {                  // w1 -> W1C f32 codes
        const float s = getscale(0);
        for (int i = tid; i < 756; i += 256)
            ws[W1C + i] = quantwc(loadT(w1, i, isbf), s);
    } else {                                 // heads + all bias codes + p-scales
        const float s0 = getscale(0), s1 = getscale(1), s2 = getscale(2);
        const float s3 = getscale(3), s4 = getscale(4), s5 = getscale(5);
        const float sa0 = ws[0], sa1 = ws[1], sa2 = ws[2], sa3 = ws[3], sa4 = ws[4];
        for (int i = tid; i < 512; i += 256) ws[BWC + i] = quantwc(loadT(bw, i, isbf), s4);
        for (int i = tid; i < 256; i += 256) ws[CWC + i] = quantwc(loadT(cw, i, isbf), s5);
        if (tid < 28)  ws[B1C + tid]  = rintf(loadT(b1, tid, isbf)  / (sa0 * s0));
        if (tid < 48)  ws[B2C + tid]  = rintf(loadT(b2, tid, isbf)  / (sa1 * s1));
        if (tid < 64)  ws[B3C + tid]  = rintf(loadT(b3, tid, isbf)  / (sa2 * s2));
        if (tid < 128) ws[FB1C + tid] = rintf(loadT(fb1, tid, isbf) / (sa3 * s3));
        if (tid < 4)   ws[BBC + tid]  = rintf(loadT(bb, tid, isbf)  / (sa4 * s4));
        if (tid < 2)   ws[CBC + tid]  = rintf(loadT(cb, tid, isbf)  / (sa4 * s5));
        if (tid == 0) {
            ws[8]  = sa0 * s0;   // p1
            ws[9]  = sa1 * s1;   // p2
            ws[10] = sa2 * s2;   // p3
            ws[11] = sa3 * s3;   // p4
            ws[12] = sa4 * s4;   // pB
            ws[13] = sa4 * s5;   // pC
        }
    }
}

// ================= main fused per-sample kernel (code domain + MFMA conv2) ====
// LDS U[9952] = 39808 B -> 4 blocks/CU.
// persistent: ACT2@0 (768), ACT3@768 (576), ACT1bf16@1344 (1694 f = 3388 bf16)
__global__ __launch_bounds__(256, 4) void k_net(
    const void* __restrict__ x, const float* __restrict__ wsr,
    float* __restrict__ outp)
{
    __shared__ __align__(16) float U[9952];
    const int tid = threadIdx.x, b = blockIdx.x;
    const float sa0 = wsr[0], sa1 = wsr[1], sa2 = wsr[2], sa3 = wsr[3];
    const float sa4 = wsr[4], sab = wsr[5], sac = wsr[6];
    const float p1 = wsr[8], p2 = wsr[9], p3 = wsr[10], p4 = wsr[11];
    const float pB = wsr[12], pC = wsr[13];
    const int isbf = wsr[15] > 0.5f;
    constexpr int ACT2F = 0, ACT3F = 768, ACT1F = 1344;
    constexpr int XQF = 3040, W1F = 4840, B1F = 5596, CMF = 5632;  // P1/P2
    constexpr int AF = 3040, BFP = 4960, C2IF = 5920, B2CF = 9889; // P3
    constexpr int W3F = 3040, B3CF = 9184;                         // P4
    constexpr int PF = 3040, A4F = 3296, PARTF = 3424;             // P5/P6

    // ---- P1: input codes + conv1 weight codes ----
    for (int i = tid; i < 1728; i += 256) {
        const float v = loadT(x, (size_t)b * 1728 + i, isbf);
        const int ci = i / 576, r = (i % 576) / 24, c = i % 24;
        U[XQF + ci * 600 + r * 25 + c] = fminf(fmaxf(rintf(v / sa0), -8.f), 7.f);
    }
    for (int i = tid; i < 756; i += 256) U[W1F + i] = wsr[W1C + i];
    if (tid < 28) U[B1F + tid] = wsr[B1C + tid];
    __syncthreads();

    // ---- P2a: conv1 by (o, conv-row, col-half): 1232 items ----
    // half 0: conv cols 0..10 -> pooled col-slots 0..4 ; half 1: cols 10..21 ->
    // slots 5..10 (col 10 recomputed; pool pairs never cross the split).
    // writes f16 colmax[28][22][11] (values <=1512, f16-exact).
    {
        _Float16* cm16 = (_Float16*)(U + CMF);
        #pragma unroll 1
        for (int item = tid; item < 1232; item += 256) {
            const int o = item / 44, rem = item % 44, r = rem >> 1, hf = rem & 1;
            const int c0 = hf ? 10 : 0;          // first conv col of this half
            const int NC = hf ? 12 : 11;         // cols processed
            float wk[27];
            #pragma unroll
            for (int i = 0; i < 27; ++i) wk[i] = U[W1F + o * 27 + i];
            float w9[27];                        // [ci][kr][slot], slot = (c-c0)%3
            #pragma unroll
            for (int ci = 0; ci < 3; ++ci)
                #pragma unroll
                for (int kr = 0; kr < 3; ++kr)
                    #pragma unroll
                    for (int j = 0; j < 2; ++j)
                        w9[ci * 9 + kr * 3 + j] =
                            U[XQF + ci * 600 + (r + kr) * 25 + (c0 + j)];
            float accP = 0.f, accC = 0.f;
            _Float16* dst = cm16 + o * 242 + r * 11 + (hf ? 5 : 0);
            #pragma unroll 1
            for (int cc = 0; cc < 12; ++cc) {
                if (!hf && cc >= 11) break;      // half 0 has 11 cols
                const int snew = (cc + 2) % 3;
                #pragma unroll
                for (int ci = 0; ci < 3; ++ci)
                    #pragma unroll
                    for (int kr = 0; kr < 3; ++kr)
                        w9[ci * 9 + kr * 3 + snew] =
                            U[XQF + ci * 600 + (r + kr) * 25 + (c0 + cc + 2)];
                float cm = 0.f;
                #pragma unroll
                for (int ci = 0; ci < 3; ++ci)
                    #pragma unroll
                    for (int kr = 0; kr < 3; ++kr)
                        #pragma unroll
                        for (int kc = 0; kc < 3; ++kc)
                            cm = fmaf(w9[ci * 9 + kr * 3 + ((cc + kc) % 3)],
                                      wk[ci * 9 + kr * 3 + kc], cm);
                // global conv col c = c0 + cc ; pooling over col pairs:
                // half0: pairs (0)(1,2)(3,4)... -> emit at even cc>=2
                // half1: c=10..21 -> cc parity matches (c even <=> cc even)
                if (cc == 0) accC = cm;
                else if (cc & 1) { accC = fmaxf(accC, cm); accP = accC; }
                else {
                    dst[cc / 2 - 1] = (_Float16)fmaxf(accP, cm);
                    accC = cm;
                }
            }
            // tail: half0 emits slot 4 from cols 8,9,10 (accP has max(c8..c10)? )
            // half0: last emit at cc=10 wrote slot 4 = max(pair c8,c9 , c10). done.
            // half1: cc ran 0..11 (c10..c21); last emit cc=10 wrote slot (5+)4 =
            //        max(c18,c19,c20); cc=11 (c21) updated accP=max(c20,c21).
            if (hf) dst[5] = (_Float16)accP;     // ceil edge: slot 10 = max(c20,c21)
        }
    }
    __syncthreads();
    // ---- P2b: pool rows (3,2,ceil) + bias + quant -> ACT1 codes bf16 ----
    {
        const _Float16* cm16 = (const _Float16*)(U + CMF);
        __hip_bfloat16* act1w = (__hip_bfloat16*)(U + ACT1F);
        for (int id = tid; id < 3388; id += 256) {
            const int o = id / 121, rem = id % 121, ph = rem / 11, pw = rem % 11;
            const int rr0 = 2 * ph;
            const _Float16* src = cm16 + o * 242 + pw;
            float mx = fmaxf((float)src[rr0 * 11], (float)src[(rr0 + 1) * 11]);
            if (rr0 + 2 < 22) mx = fmaxf(mx, (float)src[(rr0 + 2) * 11]);
            act1w[o * 121 + ph * 11 + pw] =
                __float2bfloat16(qcode(mx, U[B1F + o], p1, sa1));
        }
    }
    __syncthreads();

    // ---- P3: conv2 via MFMA (M=96 spatial, N=48 ch, K=256) + pool + quant ----
    {
        const unsigned short* act1u = (const unsigned short*)(U + ACT1F);
        unsigned short* Au = (unsigned short*)(U + AF);      // A [96][40] bf16
        unsigned short* Bu = (unsigned short*)(U + BFP);     // B [48][40] bf16 (n-major)
        const unsigned short* w2u = (const unsigned short*)(wsr + W2B);
        if (tid < 48) U[B2CF + tid] = wsr[B2C + tid];
        const int kloc = tid & 31, g = tid >> 5;
        const int wv = tid >> 6, lane = tid & 63;
        f32x4v acc[5];
        #pragma unroll
        for (int j = 0; j < 5; ++j) { acc[j][0]=0.f; acc[j][1]=0.f; acc[j][2]=0.f; acc[j][3]=0.f; }
        for (int kk = 0; kk < 8; ++kk) {
            const int k = kk * 32 + kloc;
            const bool kok = (k < 252);
            const int ci = kok ? k / 9 : 0;
            const int kr = kok ? (k % 9) / 3 : 0, kc = kok ? k % 3 : 0;
            #pragma unroll
            for (int e = 0; e < 12; ++e) {
                const int s = g + 8 * e;                 // 0..95
                unsigned short v = 0;
                if (kok && s < 81) {
                    const int r = s / 9, c = s % 9;
                    v = act1u[ci * 121 + (r + kr) * 11 + (c + kc)];
                }
                Au[s * 40 + kloc] = v;
            }
            #pragma unroll
            for (int e = 0; e < 6; ++e) {
                const int n = g + 8 * e;                 // 0..47
                Bu[n * 40 + kloc] = w2u[n * 256 + k];    // k-pad already zeroed
            }
            __syncthreads();
            #pragma unroll
            for (int j = 0; j < 5; ++j) {
                const int t = wv + 4 * j;
                if (t < 18) {
                    const int tm = t / 3, tn = t % 3;
                    bf16x8v af = *(const bf16x8v*)(Au + (tm * 16 + (lane & 15)) * 40 + (lane >> 4) * 8);
                    bf16x8v bfv = *(const bf16x8v*)(Bu + (tn * 16 + (lane & 15)) * 40 + (lane >> 4) * 8);
                    acc[j] = __builtin_amdgcn_mfma_f32_16x16x32_bf16(af, bfv, acc[j], 0, 0, 0);
                }
            }
            __syncthreads();
        }
        // scatter integer C to [81][49]
        #pragma unroll
        for (int j = 0; j < 5; ++j) {
            const int t = wv + 4 * j;
            if (t < 18) {
                const int tm = t / 3, tn = t % 3;
                const int col = tn * 16 + (lane & 15);
                #pragma unroll
                for (int r = 0; r < 4; ++r) {
                    const int row = tm * 16 + (lane >> 4) * 4 + r;
                    if (row < 81) U[C2IF + row * 49 + col] = acc[j][r];
                }
            }
        }
        __syncthreads();
        // pool(3,2) + bias + quant -> ACT2 codes [48][16]
        for (int id = tid; id < 768; id += 256) {
            const int ch = id >> 4, pp = id & 15, ph = pp >> 2, pw = pp & 3;
            float mx = -1e30f;
            #pragma unroll
            for (int r = 0; r < 3; ++r)
                #pragma unroll
                for (int c = 0; c < 3; ++c)
                    mx = fmaxf(mx, U[C2IF + ((2 * ph + r) * 9 + (2 * pw + c)) * 49 + ch]);
            U[ACT2F + ch * 16 + pp] = qcode(mx, U[B2CF + ch], p2, sa2);
        }
    }
    __syncthreads();

    // ---- P4: conv3 (all 64 ch, W3 bf16 codes in LDS; float4 staging+reads) ----
    {
        const f32x4v* src = (const f32x4v*)(wsr + W3B);
        f32x4v* dstv = (f32x4v*)(U + W3F);
        for (int i = tid; i < 1536; i += 256) dstv[i] = src[i];
    }
    if (tid < 64) U[B3CF + tid] = wsr[B3C + tid];
    __syncthreads();
    if (tid < 192) {                         // (o, hq): 64*3, 3 cols each
        const int o = tid / 3, hq = tid % 3;
        const unsigned* w3u = (const unsigned*)(U + W3F);
        float a0 = 0.f, a1 = 0.f, a2 = 0.f;
        for (int ci = 0; ci < 48; ++ci) {
            const unsigned pa = w3u[o * 96 + ci * 2];        // w00,w01
            const unsigned pb = w3u[o * 96 + ci * 2 + 1];    // w10,w11
            const float w00 = bfbits(pa & 0xffffu), w01 = bfbits(pa >> 16);
            const float w10 = bfbits(pb & 0xffffu), w11 = bfbits(pb >> 16);
            const int xb = ACT2F + ci * 16;
            const f32x4v r0 = *(const f32x4v*)(U + xb + hq * 4);        // 16B aligned
            const f32x4v r1 = *(const f32x4v*)(U + xb + (hq + 1) * 4);  // 16B aligned
            a0 = fmaf(r0[0], w00, a0); a0 = fmaf(r0[1], w01, a0);
            a0 = fmaf(r1[0], w10, a0); a0 = fmaf(r1[1], w11, a0);
            a1 = fmaf(r0[1], w00, a1); a1 = fmaf(r0[2], w01, a1);
            a1 = fmaf(r1[1], w10, a1); a1 = fmaf(r1[2], w11, a1);
            a2 = fmaf(r0[2], w00, a2); a2 = fmaf(r0[3], w01, a2);
            a2 = fmaf(r1[2], w10, a2); a2 = fmaf(r1[3], w11, a2);
        }
        const float bc = U[B3CF + o];
        U[ACT3F + o * 9 + hq * 3 + 0] = qcode(a0, bc, p3, sa3);
        U[ACT3F + o * 9 + hq * 3 + 1] = qcode(a1, bc, p3, sa3);
        U[ACT3F + o * 9 + hq * 3 + 2] = qcode(a2, bc, p3, sa3);
    }
    __syncthreads();

    // ---- P5: fc1 (576->128), paired bf16 code weights (u32 = 2 k-steps) ----
    {
        const int o = tid & 127, half = tid >> 7;
        const unsigned* fwp = (const unsigned*)(wsr + FW1B);
        float acc = 0.f;
        const int kp0 = half * 144;
        for (int kp = kp0; kp < kp0 + 144; ++kp) {
            const unsigned pr = fwp[kp * 128 + o];
            acc = fmaf(U[ACT3F + 2 * kp],     bfbits(pr & 0xffffu), acc);
            acc = fmaf(U[ACT3F + 2 * kp + 1], bfbits(pr >> 16),     acc);
        }
        U[PF + tid] = acc;
    }
    __syncthreads();
    if (tid < 128) {
        const float C = U[PF + tid] + U[PF + 128 + tid];
        U[A4F + tid] = qcode(C, wsr[FB1C + tid], p4, sa4);
    }
    __syncthreads();

    // ---- P6: heads + final signed quant ----
    if (tid < 96) {
        const int d = tid >> 4, gq = tid & 15;
        const float* hw = (d < 4) ? (wsr + BWC + d * 128) : (wsr + CWC + (d - 4) * 128);
        float p = 0.f;
        #pragma unroll
        for (int k = 0; k < 8; ++k)
            p = fmaf(U[A4F + gq * 8 + k], hw[gq * 8 + k], p);
        U[PARTF + d * 16 + gq] = p;
    }
    __syncthreads();
    if (tid < 6) {
        float C = (tid < 4) ? wsr[BBC + tid] : wsr[CBC + (tid - 4)];
        for (int g = 0; g < 16; ++g) C += U[PARTF + tid * 16 + g];
        if (tid < 4) {
            const float val = C * pB;
            outp[(size_t)b * 4 + tid] = fminf(fmaxf(rintf(val / sab), -8.f), 7.f) * sab;
        } else {
            const float val = C * pC;
            outp[16384 + (size_t)b * 2 + (tid - 4)] =
                fminf(fmaxf(rintf(val / sac), -8.f), 7.f) * sac;
        }
    }
}

// ================= fallback: R7 self-contained kernel (proven) =================
__global__ __launch_bounds__(256) void k_net_fb(
    const void* __restrict__ x,
    const void* __restrict__ w1,  const void* __restrict__ b1,
    const void* __restrict__ w2,  const void* __restrict__ b2,
    const void* __restrict__ w3,  const void* __restrict__ b3,
    const void* __restrict__ fw1, const void* __restrict__ fb1,
    const void* __restrict__ bw,  const void* __restrict__ bb,
    const void* __restrict__ cw,  const void* __restrict__ cb,
    const void* __restrict__ s0p, const void* __restrict__ s1p,
    const void* __restrict__ s2p, const void* __restrict__ s3p,
    const void* __restrict__ s4p, const void* __restrict__ s5p,
    const void* __restrict__ s6p,
    float* __restrict__ outp)
{
    __shared__ float U[16000];
    __shared__ float swsh[8];
    __shared__ float sash[8];
    const int tid = threadIdx.x;
    const int b   = blockIdx.x;
    constexpr int RED = 0, XQ = 0, W1Q = 1728, B1Q = 2484, C1 = 2512;
    constexpr int ACT1 = 9288, WB = 0, C2 = 12676, ACT2 = 14620, ACT3 = 15388;
    constexpr int A4 = 0, PART = 128;

    if (tid == 0) {
        const unsigned short* hb = (const unsigned short*)w1;
        int zeros = 0, sane = 0;
        for (int i = 0; i < 64; ++i) {
            unsigned short u = hb[2 * i];
            float v = __uint_as_float(((unsigned int)u) << 16);
            float a = fabsf(v);
            if (a == 0.f) zeros++;
            else if (a > 1e-8f && a < 1e4f) sane++;
        }
        swsh[7] = (zeros < 40 && sane >= 40) ? 1.f : 0.f;
        const void* sp[7] = { s0p, s1p, s2p, s3p, s4p, s5p, s6p };
        for (int j = 0; j < 7; ++j) {
            float v = *(const float*)sp[j];
            float a = fabsf(v);
            if (!(a > 1e-6f && a < 1e6f)) {
                double d = *(const double*)sp[j];
                double ad = fabs(d);
                if (ad > 1e-6 && ad < 1e6) v = (float)d;
                else {
                    unsigned short u = *(const unsigned short*)sp[j];
                    v = __uint_as_float(((unsigned int)u) << 16);
                }
            }
            sash[j] = v;
        }
    }
    __syncthreads();
    const int isbf = swsh[7] > 0.5f;
    {
        const void* wp[6] = { w1, w2, w3, fw1, bw, cw };
        const int   wn[6] = { 756, 12096, 12288, 73728, 512, 256 };
        for (int j = 0; j < 6; ++j) {
            float m = 0.f;
            for (int i = tid; i < wn[j]; i += 256)
                m = fmaxf(m, fabsf(loadT(wp[j], i, isbf)));
            U[RED + tid] = m; __syncthreads();
            for (int o = 128; o > 0; o >>= 1) {
                if (tid < o) U[RED + tid] = fmaxf(U[RED + tid], U[RED + tid + o]);
                __syncthreads();
            }
            if (tid == 0) swsh[j] = U[RED] / 7.0f;
            __syncthreads();
        }
    }
    const float sa0 = sash[0], sa1 = sash[1], sa2 = sash[2], sa3 = sash[3];
    const float sa4 = sash[4], sab = sash[5], sac = sash[6];
    const float sw1s = swsh[0], sw2s = swsh[1], sw3s = swsh[2];
    const float sw4s = swsh[3], swbs = swsh[4], swcs = swsh[5];

    for (int i = tid; i < 1728; i += 256) {
        float v = loadT(x, (size_t)b * 1728 + i, isbf);
        U[XQ + i] = fminf(fmaxf(rintf(v / sa0), -8.f), 7.f) * sa0;
    }
    for (int i = tid; i < 756; i += 256) U[W1Q + i] = quantw(loadT(w1, i, isbf), sw1s);
    {
        const float den = sa0 * sw1s;
        for (int i = tid; i < 28; i += 256) U[B1Q + i] = qbias(loadT(b1, i, isbf), den);
    }
    __syncthreads();

    for (int g = 0; g < 2; ++g) {
        const int obase = g * 14;
        for (int idx = tid; idx < 308; idx += 256) {
            const int ol = idx / 22, r = idx % 22, o = obase + ol;
            for (int c = 0; c < 22; ++c) {
                float acc = 0.f;
                #pragma unroll
                for (int ci = 0; ci < 3; ++ci)
                    #pragma unroll
                    for (int kr = 0; kr < 3; ++kr)
                        #pragma unroll
                        for (int kc = 0; kc < 3; ++kc)
                            acc = fmaf(U[XQ + ci * 576 + (r + kr) * 24 + (c + kc)],
                                       U[W1Q + o * 27 + ci * 9 + kr * 3 + kc], acc);
                U[C1 + ol * 484 + r * 22 + c] = acc + U[B1Q + o];
            }
        }
        __syncthreads();
        for (int i = tid; i < 1694; i += 256) {
            const int ol = i / 121, rem = i % 121, ph = rem / 11, pw = rem % 11;
            const int r0 = 2 * ph, c0 = 2 * pw;
            const int r1 = min(r0 + 3, 22), c1 = min(c0 + 3, 22);
            float mx = -1e30f;
            for (int r = r0; r < r1; ++r)
                for (int c = c0; c < c1; ++c)
                    mx = fmaxf(mx, U[C1 + ol * 484 + r * 22 + c]);
            U[ACT1 + (obase + ol) * 121 + rem] = qrelu(mx, sa1);
        }
        __syncthreads();
    }

    for (int h = 0; h < 2; ++h) {
        const int obase = h * 24;
        for (int i = tid; i < 6048; i += 256)
            U[WB + i] = quantw(loadT(w2, (size_t)h * 6048 + i, isbf), sw2s);
        {
            const float den = sa1 * sw2s;
            for (int i = tid; i < 24; i += 256)
                U[WB + 6048 + i] = qbias(loadT(b2, obase + i, isbf), den);
        }
        __syncthreads();
        for (int idx = tid; idx < 216; idx += 256) {
            const int ol = idx / 9, r = idx % 9;
            for (int c = 0; c < 9; ++c) {
                float acc = 0.f;
                for (int ci = 0; ci < 28; ++ci)
                    #pragma unroll
                    for (int kr = 0; kr < 3; ++kr)
                        #pragma unroll
                        for (int kc = 0; kc < 3; ++kc)
                            acc = fmaf(U[ACT1 + ci * 121 + (r + kr) * 11 + (c + kc)],
                                       U[WB + ol * 252 + ci * 9 + kr * 3 + kc], acc);
                U[C2 + ol * 81 + r * 9 + c] = acc + U[WB + 6048 + ol];
            }
        }
        __syncthreads();
        for (int i = tid; i < 384; i += 256) {
            const int ol = i / 16, ph = (i % 16) / 4, pw = i % 4;
            float mx = -1e30f;
            #pragma unroll
            for (int r = 0; r < 3; ++r)
                #pragma unroll
                for (int c = 0; c < 3; ++c)
                    mx = fmaxf(mx, U[C2 + ol * 81 + (2 * ph + r) * 9 + (2 * pw + c)]);
            U[ACT2 + (obase + ol) * 16 + (i % 16)] = qrelu(mx, sa2);
        }
        __syncthreads();
    }

    for (int h = 0; h < 2; ++h) {
        const int obase = h * 32;
        for (int i = tid; i < 6144; i += 256)
            U[WB + i] = quantw(loadT(w3, (size_t)h * 6144 + i, isbf), sw3s);
        {
            const float den = sa2 * sw3s;
            for (int i = tid; i < 32; i += 256)
                U[WB + 6144 + i] = qbias(loadT(b3, obase + i, isbf), den);
        }
        __syncthreads();
        for (int idx = tid; idx < 288; idx += 256) {
            const int ol = idx / 9, hh = (idx % 9) / 3, ww = idx % 3;
            float acc = 0.f;
            for (int ci = 0; ci < 48; ++ci) {
                const int xb2 = ACT2 + ci * 16;
                const int wb2 = WB + ol * 192 + ci * 4;
                acc = fmaf(U[xb2 + hh * 4 + ww],           U[wb2 + 0], acc);
                acc = fmaf(U[xb2 + hh * 4 + ww + 1],       U[wb2 + 1], acc);
                acc = fmaf(U[xb2 + (hh + 1) * 4 + ww],     U[wb2 + 2], acc);
                acc = fmaf(U[xb2 + (hh + 1) * 4 + ww + 1], U[wb2 + 3], acc);
            }
            acc += U[WB + 6144 + ol];
            U[ACT3 + (obase + ol) * 9 + hh * 3 + ww] = qrelu(acc, sa3);
        }
        __syncthreads();
    }

    {
        const int wave = tid >> 6, lane = tid & 63;
        const float den = sa3 * sw4s;
        for (int oo = 0; oo < 32; ++oo) {
            const int o = wave * 32 + oo;
            float acc = 0.f;
            #pragma unroll
            for (int j = 0; j < 9; ++j) {
                const int f = lane + 64 * j;
                const int c = f / 9, fw = (f % 9) / 3, fh = f % 3;
                const float av = U[ACT3 + c * 9 + fh * 3 + fw];
                const float wv = quantw(loadT(fw1, (size_t)o * 576 + f, isbf), sw4s);
                acc = fmaf(av, wv, acc);
            }
            #pragma unroll
            for (int off = 32; off > 0; off >>= 1)
                acc += __shfl_down(acc, off);
            if (lane == 0) {
                acc += qbias(loadT(fb1, o, isbf), den);
                U[A4 + o] = qrelu(acc, sa4);
            }
        }
    }
    __syncthreads();

    if (tid < 96) {
        const int d = tid >> 4, g = tid & 15;
        const void* hw = (d < 4) ? bw : cw;
        const int row = (d < 4) ? d : d - 4;
        const float swh = (d < 4) ? swbs : swcs;
        float p = 0.f;
        #pragma unroll
        for (int k = 0; k < 8; ++k) {
            const int kk = g * 8 + k;
            p = fmaf(U[A4 + kk], quantw(loadT(hw, row * 128 + kk, isbf), swh), p);
        }
        U[PART + d * 16 + g] = p;
    }
    __syncthreads();
    if (tid < 6) {
        const int d = tid;
        float acc;
        if (d < 4) acc = qbias(loadT(bb, d, isbf), sa4 * swbs);
        else       acc = qbias(loadT(cb, d - 4, isbf), sa4 * swcs);
        for (int g = 0; g < 16; ++g) acc += U[PART + d * 16 + g];
        if (d < 4) outp[(size_t)b * 4 + d] = fminf(fmaxf(rintf(acc / sab), -8.f), 7.f) * sab;
        else outp[16384 + (size_t)b * 2 + (d - 4)] = fminf(fmaxf(rintf(acc / sac), -8.f), 7.f) * sac;
    }
}

extern "C" void kernel_launch(void* const* d_in, const int* in_sizes, int n_in,
                              void* d_out, int out_size, void* d_ws, size_t ws_size,
                              hipStream_t stream)
{
    float* out = (float*)d_out;
    const int expect[20] = { 7077888, 756, 28, 12096, 48, 12288, 64, 73728, 128,
                             512, 4, 256, 2, 1, 1, 1, 1, 1, 1, 1 };
    if (n_in < 20) { k_beacon<<<1, 64, 0, stream>>>(out, 9000.f); return; }
    for (int i = 0; i < 20; ++i)
        if (in_sizes[i] != expect[i]) {
            k_beacon<<<1, 64, 0, stream>>>(out, 2000.f + 10.f * i);
            return;
        }

    if (ws_size >= (size_t)100000 * sizeof(float)) {
        float* ws = (float*)d_ws;
        k_scale<<<35, 256, 0, stream>>>(
            d_in[1], d_in[3], d_in[5], d_in[7], d_in[9], d_in[11],
            d_in[13], d_in[14], d_in[15], d_in[16], d_in[17], d_in[18], d_in[19],
            ws);
        k_quant<<<34, 256, 0, stream>>>(
            d_in[1], d_in[2], d_in[3], d_in[4], d_in[5], d_in[6],
            d_in[7], d_in[8], d_in[9], d_in[10], d_in[11], d_in[12],
            ws);
        k_net<<<4096, 256, 0, stream>>>(d_in[0], ws, out);
    } else {
        k_net_fb<<<4096, 256, 0, stream>>>(
            d_in[0], d_in[1], d_in[2], d_in[3], d_in[4], d_in[5], d_in[6],
            d_in[7], d_in[8], d_in[9], d_in[10], d_in[11], d_in[12],
            d_in[13], d_in[14], d_in[15], d_in[16], d_in[17], d_in[18], d_in[19],
            out);
    }
}

// Round 16
// 200.298 us; speedup vs baseline: 1.6834x; 1.6834x over previous
//
#include <hip/hip_runtime.h>
#include <hip/hip_bf16.h>
#include <math.h>

typedef __attribute__((ext_vector_type(8))) short bf16x8v;   // 8 bf16 (4 VGPR)
typedef __attribute__((ext_vector_type(4))) float f32x4v;

// ================= shared helpers =================
__device__ __forceinline__ float loadT(const void* p, size_t i, int isbf) {
    if (isbf) return __bfloat162float(((const __hip_bfloat16*)p)[i]);
    return ((const float*)p)[i];
}
__device__ __forceinline__ float quantw(float v, float s) {      // weight VALUE
    return fminf(fmaxf(rintf(v / s), -7.f), 7.f) * s;
}
__device__ __forceinline__ float quantwc(float v, float s) {     // weight CODE
    return fminf(fmaxf(rintf(v / s), -7.f), 7.f);
}
__device__ __forceinline__ float qbias(float v, float den) {     // Int32Bias VALUE
    return rintf(v / den) * den;
}
__device__ __forceinline__ float qrelu(float v, float s) {       // [0,15] VALUE
    return fminf(fmaxf(rintf(fmaxf(v, 0.f) / s), 0.f), 15.f) * s;
}
// code-domain quant-relu: Cint+bias code -> next-layer code
__device__ __forceinline__ float qcode(float Cint, float bcode, float p, float snext) {
    float v = (Cint + bcode) * p;
    return fminf(fmaxf(rintf(fmaxf(v, 0.f) / snext), 0.f), 15.f);
}
__device__ __forceinline__ float bfbits(unsigned u) {            // bf16 bits -> f32
    return __uint_as_float(u << 16);
}

__global__ void k_beacon(float* out, float code) {
    if (threadIdx.x == 0 && blockIdx.x == 0) out[0] = code;
}

// ================= ws layout (floats) =================
// [0..6]=sa0..sa4,sab,sac ; [8..13]=p1,p2,p3,p4,pB,pC ; [15]=isbf
static constexpr int W1C  = 16;     // 756   f32 codes (conv1)
static constexpr int B1C  = 772;    // 28    f32 codes
static constexpr int B2C  = 800;    // 48
static constexpr int B3C  = 848;    // 64
static constexpr int FB1C = 912;    // 128
static constexpr int BBC  = 1040;   // 4
static constexpr int CBC  = 1044;   // 2
static constexpr int FW1B = 1048;   // 36864 floats = 73728 bf16 codes, PAIRED [k/2][128][2]
static constexpr int W2B  = 37912;  // 6144 floats = 12288 bf16 codes [48][256] (k-pad)
static constexpr int W3B  = 44056;  // 6144 floats = 12288 bf16 codes [64][48][2][2]
static constexpr int BWC  = 50200;  // 512  f32 codes
static constexpr int CWC  = 50712;  // 256  f32 codes
static constexpr int PMAXF = 51000; // 35 partial-max slots

// chunks per tensor {w1,w2,w3,fw1,bw,cw} and block-offset prefix
__device__ __constant__ int d_CHK[6]  = { 1, 4, 4, 24, 1, 1 };
__device__ __constant__ int d_POFF[7] = { 0, 1, 5, 9, 33, 34, 35 };

// ============ k_scale: partial maxes (35 blocks) + probe + act scales ============
__global__ __launch_bounds__(256) void k_scale(
    const void* w1, const void* w2, const void* w3, const void* fw1,
    const void* bw, const void* cw,
    const void* s0p, const void* s1p, const void* s2p, const void* s3p,
    const void* s4p, const void* s5p, const void* s6p,
    float* __restrict__ ws)
{
    __shared__ float red[256];
    __shared__ float shisbf;
    const int tid = threadIdx.x, blk = blockIdx.x;
    // wave-parallel storage-format probe (1 load/lane + ballot)
    if (tid < 64) {
        const unsigned short* hb = (const unsigned short*)w1;
        const float a = fabsf(bfbits((unsigned)hb[2 * tid]));
        const unsigned long long bz = __ballot(a == 0.f);
        const unsigned long long bs = __ballot(a > 1e-8f && a < 1e4f);
        if (tid == 0) {
            const int zeros = __popcll(bz), sane = __popcll(bs);
            shisbf = (zeros < 40 && sane >= 40) ? 1.f : 0.f;
        }
    }
    __syncthreads();
    const int isbf = shisbf > 0.5f;
    if (blk == 0) {
        if (tid == 7) ws[15] = shisbf;
        if (tid < 7) {                       // 7 scales read in parallel
            const void* sp[7] = { s0p, s1p, s2p, s3p, s4p, s5p, s6p };
            const void* p = sp[tid];
            float v = *(const float*)p;
            float a = fabsf(v);
            if (!(a > 1e-6f && a < 1e6f)) {
                double d = *(const double*)p;
                double ad = fabs(d);
                if (ad > 1e-6 && ad < 1e6) v = (float)d;
                else v = bfbits((unsigned)(*(const unsigned short*)p));
            }
            ws[tid] = v;
        }
    }
    // tensor/chunk for this block
    int j = 0;
    while (j < 5 && blk >= d_POFF[j + 1]) ++j;
    const int c = blk - d_POFF[j];
    const void* wp[6] = { w1, w2, w3, fw1, bw, cw };
    const int   wn[6] = { 756, 12096, 12288, 73728, 512, 256 };
    const int nw = wn[j];
    const int len = (nw + d_CHK[j] - 1) / d_CHK[j];
    const int i0 = c * len, i1 = min(i0 + len, nw);
    float m = 0.f;
    for (int i = i0 + tid; i < i1; i += 256)
        m = fmaxf(m, fabsf(loadT(wp[j], i, isbf)));
    red[tid] = m; __syncthreads();
    for (int o = 128; o > 0; o >>= 1) {
        if (tid < o) red[tid] = fmaxf(red[tid], red[tid + o]);
        __syncthreads();
    }
    if (tid == 0) ws[PMAXF + blk] = red[0];
}

// ============ k_quant: quantize all weights/biases (34 blocks, short trips) ======
__global__ __launch_bounds__(256) void k_quant(
    const void* w1, const void* b1, const void* w2, const void* b2,
    const void* w3, const void* b3, const void* fw1, const void* fb1,
    const void* bw, const void* bb, const void* cw, const void* cb,
    float* __restrict__ ws)
{
    const int tid = threadIdx.x, blk = blockIdx.x;
    const int isbf = ws[15] > 0.5f;
    auto getscale = [&](int j) {
        float m = 0.f;
        for (int t = d_POFF[j]; t < d_POFF[j + 1]; ++t)
            m = fmaxf(m, ws[PMAXF + t]);
        return m / 7.0f;
    };

    if (blk < 24) {                          // fw1 -> FW1B bf16, paired [kk/2][128][2]
        const float s = getscale(3);
        const int i0 = blk * 3072, i1 = min(i0 + 3072, 73728);
        __hip_bfloat16* dst = (__hip_bfloat16*)(ws + FW1B);
        for (int i = i0 + tid; i < i1; i += 256) {
            const float q = quantwc(loadT(fw1, i, isbf), s);
            const int o = i / 576, f = i % 576;
            const int c = f / 9, fw_ = (f % 9) / 3, fh = f % 3;
            const int kk = c * 9 + fh * 3 + fw_;        // act3 flat k (flatten folded)
            dst[(kk >> 1) * 256 + o * 2 + (kk & 1)] = __float2bfloat16(q);
        }
    } else if (blk < 28) {                   // w2 -> W2B bf16 [48][256]
        const float s = getscale(1);
        const int c = blk - 24;
        const int i0 = c * 3024, i1 = min(i0 + 3024, 12096);
        __hip_bfloat16* dst = (__hip_bfloat16*)(ws + W2B);
        for (int i = i0 + tid; i < i1; i += 256) {
            const float q = quantwc(loadT(w2, i, isbf), s);
            const int n = i / 252, k = i % 252;
            dst[n * 256 + k] = __float2bfloat16(q);
        }
        if (c == 0) {                        // zero-pad k = 252..255
            for (int i = tid; i < 192; i += 256) {
                const int n = i / 4, k = 252 + (i % 4);
                dst[n * 256 + k] = __float2bfloat16(0.f);
            }
        }
    } else if (blk < 32) {                   // w3 -> W3B bf16 [i]
        const float s = getscale(2);
        const int c = blk - 28;
        const int i0 = c * 3072, i1 = min(i0 + 3072, 12288);
        __hip_bfloat16* dst = (__hip_bfloat16*)(ws + W3B);
        for (int i = i0 + tid; i < i1; i += 256)
            dst[i] = __float2bfloat16(quantwc(loadT(w3, i, isbf), s));
    } else if (blk == 32) {                  // w1 -> W1C f32 codes
        const float s = getscale(0);
        for (int i = tid; i < 756; i += 256)
            ws[W1C + i] = quantwc(loadT(w1, i, isbf), s);
    } else {                                 // heads + all bias codes + p-scales
        const float s0 = getscale(0), s1 = getscale(1), s2 = getscale(2);
        const float s3 = getscale(3), s4 = getscale(4), s5 = getscale(5);
        const float sa0 = ws[0], sa1 = ws[1], sa2 = ws[2], sa3 = ws[3], sa4 = ws[4];
        for (int i = tid; i < 512; i += 256) ws[BWC + i] = quantwc(loadT(bw, i, isbf), s4);
        for (int i = tid; i < 256; i += 256) ws[CWC + i] = quantwc(loadT(cw, i, isbf), s5);
        if (tid < 28)  ws[B1C + tid]  = rintf(loadT(b1, tid, isbf)  / (sa0 * s0));
        if (tid < 48)  ws[B2C + tid]  = rintf(loadT(b2, tid, isbf)  / (sa1 * s1));
        if (tid < 64)  ws[B3C + tid]  = rintf(loadT(b3, tid, isbf)  / (sa2 * s2));
        if (tid < 128) ws[FB1C + tid] = rintf(loadT(fb1, tid, isbf) / (sa3 * s3));
        if (tid < 4)   ws[BBC + tid]  = rintf(loadT(bb, tid, isbf)  / (sa4 * s4));
        if (tid < 2)   ws[CBC + tid]  = rintf(loadT(cb, tid, isbf)  / (sa4 * s5));
        if (tid == 0) {
            ws[8]  = sa0 * s0;   // p1
            ws[9]  = sa1 * s1;   // p2
            ws[10] = sa2 * s2;   // p3
            ws[11] = sa3 * s3;   // p4
            ws[12] = sa4 * s4;   // pB
            ws[13] = sa4 * s5;   // pC
        }
    }
}

// ================= main fused per-sample kernel (code domain + MFMA conv2) ====
// LDS U[9952] = 39808 B -> 4 blocks/CU.
// persistent: ACT2@0 (768), ACT3@768 (576), ACT1bf16@1344 (1694 f = 3388 bf16)
__global__ __launch_bounds__(256, 4) void k_net(
    const void* __restrict__ x, const float* __restrict__ wsr,
    float* __restrict__ outp)
{
    __shared__ __align__(16) float U[9952];
    const int tid = threadIdx.x, b = blockIdx.x;
    const float sa0 = wsr[0], sa1 = wsr[1], sa2 = wsr[2], sa3 = wsr[3];
    const float sa4 = wsr[4], sab = wsr[5], sac = wsr[6];
    const float p1 = wsr[8], p2 = wsr[9], p3 = wsr[10], p4 = wsr[11];
    const float pB = wsr[12], pC = wsr[13];
    const int isbf = wsr[15] > 0.5f;
    constexpr int ACT2F = 0, ACT3F = 768, ACT1F = 1344;
    constexpr int XQF = 3040, W1F = 4840, B1F = 5596, CMF = 5632;  // P1/P2
    constexpr int AF = 3040, BFP = 4960, C2IF = 5920, B2CF = 9889; // P3
    constexpr int W3F = 3040, B3CF = 9184;                         // P4
    constexpr int PF = 3040, A4F = 3296, PARTF = 3424;             // P5/P6

    // ---- P1: input codes + conv1 weight codes ----
    for (int i = tid; i < 1728; i += 256) {
        const float v = loadT(x, (size_t)b * 1728 + i, isbf);
        const int ci = i / 576, r = (i % 576) / 24, c = i % 24;
        U[XQF + ci * 600 + r * 25 + c] = fminf(fmaxf(rintf(v / sa0), -8.f), 7.f);
    }
    for (int i = tid; i < 756; i += 256) U[W1F + i] = wsr[W1C + i];
    if (tid < 28) U[B1F + tid] = wsr[B1C + tid];
    __syncthreads();

    // ---- P2a: conv1 by (o, conv-row): 616 items, modular sliding window ----
    // each item computes one conv row (22 cols), streams 11 col-pooled maxima
    // into f16 colmax[28][22][11] (values <=1512, f16-exact).
    {
        _Float16* cm16 = (_Float16*)(U + CMF);
        #pragma unroll 1
        for (int item = tid; item < 616; item += 256) {
            const int o = item / 22, r = item % 22;
            float wk[27];
            #pragma unroll
            for (int i = 0; i < 27; ++i) wk[i] = U[W1F + o * 27 + i];
            float w9[27];                   // [ci][kr][slot], slot = col%3
            #pragma unroll
            for (int ci = 0; ci < 3; ++ci)
                #pragma unroll
                for (int kr = 0; kr < 3; ++kr)
                    #pragma unroll
                    for (int j = 0; j < 2; ++j)
                        w9[ci * 9 + kr * 3 + j] = U[XQF + ci * 600 + (r + kr) * 25 + j];
            float accP = 0.f, accC = 0.f;
            _Float16* dst = cm16 + o * 242 + r * 11;
            #pragma unroll
            for (int c = 0; c < 22; ++c) {
                const int snew = (c + 2) % 3;
                #pragma unroll
                for (int ci = 0; ci < 3; ++ci)
                    #pragma unroll
                    for (int kr = 0; kr < 3; ++kr)
                        w9[ci * 9 + kr * 3 + snew] =
                            U[XQF + ci * 600 + (r + kr) * 25 + (c + 2)];
                float cm = 0.f;
                #pragma unroll
                for (int ci = 0; ci < 3; ++ci)
                    #pragma unroll
                    for (int kr = 0; kr < 3; ++kr)
                        #pragma unroll
                        for (int kc = 0; kc < 3; ++kc)
                            cm = fmaf(w9[ci * 9 + kr * 3 + ((c + kc) % 3)],
                                      wk[ci * 9 + kr * 3 + kc], cm);
                if (c == 0) accC = cm;
                else if (c & 1) { accC = fmaxf(accC, cm); accP = accC; }
                else { dst[c / 2 - 1] = (_Float16)fmaxf(accP, cm); accC = cm; }
            }
            dst[10] = (_Float16)accP;       // ceil-mode col edge (cols 20,21)
        }
    }
    __syncthreads();
    // ---- P2b: pool rows (3,2,ceil) + bias + quant -> ACT1 codes bf16 ----
    {
        const _Float16* cm16 = (const _Float16*)(U + CMF);
        __hip_bfloat16* act1w = (__hip_bfloat16*)(U + ACT1F);
        for (int id = tid; id < 3388; id += 256) {
            const int o = id / 121, rem = id % 121, ph = rem / 11, pw = rem % 11;
            const int rr0 = 2 * ph;
            const _Float16* src = cm16 + o * 242 + pw;
            float mx = fmaxf((float)src[rr0 * 11], (float)src[(rr0 + 1) * 11]);
            if (rr0 + 2 < 22) mx = fmaxf(mx, (float)src[(rr0 + 2) * 11]);
            act1w[o * 121 + ph * 11 + pw] =
                __float2bfloat16(qcode(mx, U[B1F + o], p1, sa1));
        }
    }
    __syncthreads();

    // ---- P3: conv2 via MFMA (M=96 spatial, N=48 ch, K=256) + pool + quant ----
    {
        const unsigned short* act1u = (const unsigned short*)(U + ACT1F);
        unsigned short* Au = (unsigned short*)(U + AF);      // A [96][40] bf16
        unsigned short* Bu = (unsigned short*)(U + BFP);     // B [48][40] bf16 (n-major)
        const unsigned short* w2u = (const unsigned short*)(wsr + W2B);
        if (tid < 48) U[B2CF + tid] = wsr[B2C + tid];
        const int kloc = tid & 31, g = tid >> 5;
        const int wv = tid >> 6, lane = tid & 63;
        f32x4v acc[5];
        #pragma unroll
        for (int j = 0; j < 5; ++j) { acc[j][0]=0.f; acc[j][1]=0.f; acc[j][2]=0.f; acc[j][3]=0.f; }
        for (int kk = 0; kk < 8; ++kk) {
            const int k = kk * 32 + kloc;
            const bool kok = (k < 252);
            const int ci = kok ? k / 9 : 0;
            const int kr = kok ? (k % 9) / 3 : 0, kc = kok ? k % 3 : 0;
            #pragma unroll
            for (int e = 0; e < 12; ++e) {
                const int s = g + 8 * e;                 // 0..95
                unsigned short v = 0;
                if (kok && s < 81) {
                    const int r = s / 9, c = s % 9;
                    v = act1u[ci * 121 + (r + kr) * 11 + (c + kc)];
                }
                Au[s * 40 + kloc] = v;
            }
            #pragma unroll
            for (int e = 0; e < 6; ++e) {
                const int n = g + 8 * e;                 // 0..47
                Bu[n * 40 + kloc] = w2u[n * 256 + k];    // k-pad already zeroed
            }
            __syncthreads();
            #pragma unroll
            for (int j = 0; j < 5; ++j) {
                const int t = wv + 4 * j;
                if (t < 18) {
                    const int tm = t / 3, tn = t % 3;
                    bf16x8v af = *(const bf16x8v*)(Au + (tm * 16 + (lane & 15)) * 40 + (lane >> 4) * 8);
                    bf16x8v bfv = *(const bf16x8v*)(Bu + (tn * 16 + (lane & 15)) * 40 + (lane >> 4) * 8);
                    acc[j] = __builtin_amdgcn_mfma_f32_16x16x32_bf16(af, bfv, acc[j], 0, 0, 0);
                }
            }
            __syncthreads();
        }
        // scatter integer C to [81][49]
        #pragma unroll
        for (int j = 0; j < 5; ++j) {
            const int t = wv + 4 * j;
            if (t < 18) {
                const int tm = t / 3, tn = t % 3;
                const int col = tn * 16 + (lane & 15);
                #pragma unroll
                for (int r = 0; r < 4; ++r) {
                    const int row = tm * 16 + (lane >> 4) * 4 + r;
                    if (row < 81) U[C2IF + row * 49 + col] = acc[j][r];
                }
            }
        }
        __syncthreads();
        // pool(3,2) + bias + quant -> ACT2 codes [48][16]
        for (int id = tid; id < 768; id += 256) {
            const int ch = id >> 4, pp = id & 15, ph = pp >> 2, pw = pp & 3;
            float mx = -1e30f;
            #pragma unroll
            for (int r = 0; r < 3; ++r)
                #pragma unroll
                for (int c = 0; c < 3; ++c)
                    mx = fmaxf(mx, U[C2IF + ((2 * ph + r) * 9 + (2 * pw + c)) * 49 + ch]);
            U[ACT2F + ch * 16 + pp] = qcode(mx, U[B2CF + ch], p2, sa2);
        }
    }
    __syncthreads();

    // ---- P4: conv3 (all 64 ch, W3 bf16 codes in LDS; float4 staging+reads) ----
    {
        const f32x4v* src = (const f32x4v*)(wsr + W3B);
        f32x4v* dstv = (f32x4v*)(U + W3F);
        for (int i = tid; i < 1536; i += 256) dstv[i] = src[i];
    }
    if (tid < 64) U[B3CF + tid] = wsr[B3C + tid];
    __syncthreads();
    if (tid < 192) {                         // (o, hq): 64*3, 3 cols each
        const int o = tid / 3, hq = tid % 3;
        const unsigned* w3u = (const unsigned*)(U + W3F);
        float a0 = 0.f, a1 = 0.f, a2 = 0.f;
        for (int ci = 0; ci < 48; ++ci) {
            const unsigned pa = w3u[o * 96 + ci * 2];        // w00,w01
            const unsigned pb = w3u[o * 96 + ci * 2 + 1];    // w10,w11
            const float w00 = bfbits(pa & 0xffffu), w01 = bfbits(pa >> 16);
            const float w10 = bfbits(pb & 0xffffu), w11 = bfbits(pb >> 16);
            const int xb = ACT2F + ci * 16;
            const f32x4v r0 = *(const f32x4v*)(U + xb + hq * 4);        // 16B aligned
            const f32x4v r1 = *(const f32x4v*)(U + xb + (hq + 1) * 4);  // 16B aligned
            a0 = fmaf(r0[0], w00, a0); a0 = fmaf(r0[1], w01, a0);
            a0 = fmaf(r1[0], w10, a0); a0 = fmaf(r1[1], w11, a0);
            a1 = fmaf(r0[1], w00, a1); a1 = fmaf(r0[2], w01, a1);
            a1 = fmaf(r1[1], w10, a1); a1 = fmaf(r1[2], w11, a1);
            a2 = fmaf(r0[2], w00, a2); a2 = fmaf(r0[3], w01, a2);
            a2 = fmaf(r1[2], w10, a2); a2 = fmaf(r1[3], w11, a2);
        }
        const float bc = U[B3CF + o];
        U[ACT3F + o * 9 + hq * 3 + 0] = qcode(a0, bc, p3, sa3);
        U[ACT3F + o * 9 + hq * 3 + 1] = qcode(a1, bc, p3, sa3);
        U[ACT3F + o * 9 + hq * 3 + 2] = qcode(a2, bc, p3, sa3);
    }
    __syncthreads();

    // ---- P5: fc1 (576->128), paired bf16 code weights (u32 = 2 k-steps) ----
    {
        const int o = tid & 127, half = tid >> 7;
        const unsigned* fwp = (const unsigned*)(wsr + FW1B);
        float acc = 0.f;
        const int kp0 = half * 144;
        for (int kp = kp0; kp < kp0 + 144; ++kp) {
            const unsigned pr = fwp[kp * 128 + o];
            acc = fmaf(U[ACT3F + 2 * kp],     bfbits(pr & 0xffffu), acc);
            acc = fmaf(U[ACT3F + 2 * kp + 1], bfbits(pr >> 16),     acc);
        }
        U[PF + tid] = acc;
    }
    __syncthreads();
    if (tid < 128) {
        const float C = U[PF + tid] + U[PF + 128 + tid];
        U[A4F + tid] = qcode(C, wsr[FB1C + tid], p4, sa4);
    }
    __syncthreads();

    // ---- P6: heads + final signed quant ----
    if (tid < 96) {
        const int d = tid >> 4, gq = tid & 15;
        const float* hw = (d < 4) ? (wsr + BWC + d * 128) : (wsr + CWC + (d - 4) * 128);
        float p = 0.f;
        #pragma unroll
        for (int k = 0; k < 8; ++k)
            p = fmaf(U[A4F + gq * 8 + k], hw[gq * 8 + k], p);
        U[PARTF + d * 16 + gq] = p;
    }
    __syncthreads();
    if (tid < 6) {
        float C = (tid < 4) ? wsr[BBC + tid] : wsr[CBC + (tid - 4)];
        for (int g = 0; g < 16; ++g) C += U[PARTF + tid * 16 + g];
        if (tid < 4) {
            const float val = C * pB;
            outp[(size_t)b * 4 + tid] = fminf(fmaxf(rintf(val / sab), -8.f), 7.f) * sab;
        } else {
            const float val = C * pC;
            outp[16384 + (size_t)b * 2 + (tid - 4)] =
                fminf(fmaxf(rintf(val / sac), -8.f), 7.f) * sac;
        }
    }
}

// ================= fallback: R7 self-contained kernel (proven) =================
__global__ __launch_bounds__(256) void k_net_fb(
    const void* __restrict__ x,
    const void* __restrict__ w1,  const void* __restrict__ b1,
    const void* __restrict__ w2,  const void* __restrict__ b2,
    const void* __restrict__ w3,  const void* __restrict__ b3,
    const void* __restrict__ fw1, const void* __restrict__ fb1,
    const void* __restrict__ bw,  const void* __restrict__ bb,
    const void* __restrict__ cw,  const void* __restrict__ cb,
    const void* __restrict__ s0p, const void* __restrict__ s1p,
    const void* __restrict__ s2p, const void* __restrict__ s3p,
    const void* __restrict__ s4p, const void* __restrict__ s5p,
    const void* __restrict__ s6p,
    float* __restrict__ outp)
{
    __shared__ float U[16000];
    __shared__ float swsh[8];
    __shared__ float sash[8];
    const int tid = threadIdx.x;
    const int b   = blockIdx.x;
    constexpr int RED = 0, XQ = 0, W1Q = 1728, B1Q = 2484, C1 = 2512;
    constexpr int ACT1 = 9288, WB = 0, C2 = 12676, ACT2 = 14620, ACT3 = 15388;
    constexpr int A4 = 0, PART = 128;

    if (tid == 0) {
        const unsigned short* hb = (const unsigned short*)w1;
        int zeros = 0, sane = 0;
        for (int i = 0; i < 64; ++i) {
            unsigned short u = hb[2 * i];
            float v = __uint_as_float(((unsigned int)u) << 16);
            float a = fabsf(v);
            if (a == 0.f) zeros++;
            else if (a > 1e-8f && a < 1e4f) sane++;
        }
        swsh[7] = (zeros < 40 && sane >= 40) ? 1.f : 0.f;
        const void* sp[7] = { s0p, s1p, s2p, s3p, s4p, s5p, s6p };
        for (int j = 0; j < 7; ++j) {
            float v = *(const float*)sp[j];
            float a = fabsf(v);
            if (!(a > 1e-6f && a < 1e6f)) {
                double d = *(const double*)sp[j];
                double ad = fabs(d);
                if (ad > 1e-6 && ad < 1e6) v = (float)d;
                else {
                    unsigned short u = *(const unsigned short*)sp[j];
                    v = __uint_as_float(((unsigned int)u) << 16);
                }
            }
            sash[j] = v;
        }
    }
    __syncthreads();
    const int isbf = swsh[7] > 0.5f;
    {
        const void* wp[6] = { w1, w2, w3, fw1, bw, cw };
        const int   wn[6] = { 756, 12096, 12288, 73728, 512, 256 };
        for (int j = 0; j < 6; ++j) {
            float m = 0.f;
            for (int i = tid; i < wn[j]; i += 256)
                m = fmaxf(m, fabsf(loadT(wp[j], i, isbf)));
            U[RED + tid] = m; __syncthreads();
            for (int o = 128; o > 0; o >>= 1) {
                if (tid < o) U[RED + tid] = fmaxf(U[RED + tid], U[RED + tid + o]);
                __syncthreads();
            }
            if (tid == 0) swsh[j] = U[RED] / 7.0f;
            __syncthreads();
        }
    }
    const float sa0 = sash[0], sa1 = sash[1], sa2 = sash[2], sa3 = sash[3];
    const float sa4 = sash[4], sab = sash[5], sac = sash[6];
    const float sw1s = swsh[0], sw2s = swsh[1], sw3s = swsh[2];
    const float sw4s = swsh[3], swbs = swsh[4], swcs = swsh[5];

    for (int i = tid; i < 1728; i += 256) {
        float v = loadT(x, (size_t)b * 1728 + i, isbf);
        U[XQ + i] = fminf(fmaxf(rintf(v / sa0), -8.f), 7.f) * sa0;
    }
    for (int i = tid; i < 756; i += 256) U[W1Q + i] = quantw(loadT(w1, i, isbf), sw1s);
    {
        const float den = sa0 * sw1s;
        for (int i = tid; i < 28; i += 256) U[B1Q + i] = qbias(loadT(b1, i, isbf), den);
    }
    __syncthreads();

    for (int g = 0; g < 2; ++g) {
        const int obase = g * 14;
        for (int idx = tid; idx < 308; idx += 256) {
            const int ol = idx / 22, r = idx % 22, o = obase + ol;
            for (int c = 0; c < 22; ++c) {
                float acc = 0.f;
                #pragma unroll
                for (int ci = 0; ci < 3; ++ci)
                    #pragma unroll
                    for (int kr = 0; kr < 3; ++kr)
                        #pragma unroll
                        for (int kc = 0; kc < 3; ++kc)
                            acc = fmaf(U[XQ + ci * 576 + (r + kr) * 24 + (c + kc)],
                                       U[W1Q + o * 27 + ci * 9 + kr * 3 + kc], acc);
                U[C1 + ol * 484 + r * 22 + c] = acc + U[B1Q + o];
            }
        }
        __syncthreads();
        for (int i = tid; i < 1694; i += 256) {
            const int ol = i / 121, rem = i % 121, ph = rem / 11, pw = rem % 11;
            const int r0 = 2 * ph, c0 = 2 * pw;
            const int r1 = min(r0 + 3, 22), c1 = min(c0 + 3, 22);
            float mx = -1e30f;
            for (int r = r0; r < r1; ++r)
                for (int c = c0; c < c1; ++c)
                    mx = fmaxf(mx, U[C1 + ol * 484 + r * 22 + c]);
            U[ACT1 + (obase + ol) * 121 + rem] = qrelu(mx, sa1);
        }
        __syncthreads();
    }

    for (int h = 0; h < 2; ++h) {
        const int obase = h * 24;
        for (int i = tid; i < 6048; i += 256)
            U[WB + i] = quantw(loadT(w2, (size_t)h * 6048 + i, isbf), sw2s);
        {
            const float den = sa1 * sw2s;
            for (int i = tid; i < 24; i += 256)
                U[WB + 6048 + i] = qbias(loadT(b2, obase + i, isbf), den);
        }
        __syncthreads();
        for (int idx = tid; idx < 216; idx += 256) {
            const int ol = idx / 9, r = idx % 9;
            for (int c = 0; c < 9; ++c) {
                float acc = 0.f;
                for (int ci = 0; ci < 28; ++ci)
                    #pragma unroll
                    for (int kr = 0; kr < 3; ++kr)
                        #pragma unroll
                        for (int kc = 0; kc < 3; ++kc)
                            acc = fmaf(U[ACT1 + ci * 121 + (r + kr) * 11 + (c + kc)],
                                       U[WB + ol * 252 + ci * 9 + kr * 3 + kc], acc);
                U[C2 + ol * 81 + r * 9 + c] = acc + U[WB + 6048 + ol];
            }
        }
        __syncthreads();
        for (int i = tid; i < 384; i += 256) {
            const int ol = i / 16, ph = (i % 16) / 4, pw = i % 4;
            float mx = -1e30f;
            #pragma unroll
            for (int r = 0; r < 3; ++r)
                #pragma unroll
                for (int c = 0; c < 3; ++c)
                    mx = fmaxf(mx, U[C2 + ol * 81 + (2 * ph + r) * 9 + (2 * pw + c)]);
            U[ACT2 + (obase + ol) * 16 + (i % 16)] = qrelu(mx, sa2);
        }
        __syncthreads();
    }

    for (int h = 0; h < 2; ++h) {
        const int obase = h * 32;
        for (int i = tid; i < 6144; i += 256)
            U[WB + i] = quantw(loadT(w3, (size_t)h * 6144 + i, isbf), sw3s);
        {
            const float den = sa2 * sw3s;
            for (int i = tid; i < 32; i += 256)
                U[WB + 6144 + i] = qbias(loadT(b3, obase + i, isbf), den);
        }
        __syncthreads();
        for (int idx = tid; idx < 288; idx += 256) {
            const int ol = idx / 9, hh = (idx % 9) / 3, ww = idx % 3;
            float acc = 0.f;
            for (int ci = 0; ci < 48; ++ci) {
                const int xb2 = ACT2 + ci * 16;
                const int wb2 = WB + ol * 192 + ci * 4;
                acc = fmaf(U[xb2 + hh * 4 + ww],           U[wb2 + 0], acc);
                acc = fmaf(U[xb2 + hh * 4 + ww + 1],       U[wb2 + 1], acc);
                acc = fmaf(U[xb2 + (hh + 1) * 4 + ww],     U[wb2 + 2], acc);
                acc = fmaf(U[xb2 + (hh + 1) * 4 + ww + 1], U[wb2 + 3], acc);
            }
            acc += U[WB + 6144 + ol];
            U[ACT3 + (obase + ol) * 9 + hh * 3 + ww] = qrelu(acc, sa3);
        }
        __syncthreads();
    }

    {
        const int wave = tid >> 6, lane = tid & 63;
        const float den = sa3 * sw4s;
        for (int oo = 0; oo < 32; ++oo) {
            const int o = wave * 32 + oo;
            float acc = 0.f;
            #pragma unroll
            for (int j = 0; j < 9; ++j) {
                const int f = lane + 64 * j;
                const int c = f / 9, fw = (f % 9) / 3, fh = f % 3;
                const float av = U[ACT3 + c * 9 + fh * 3 + fw];
                const float wv = quantw(loadT(fw1, (size_t)o * 576 + f, isbf), sw4s);
                acc = fmaf(av, wv, acc);
            }
            #pragma unroll
            for (int off = 32; off > 0; off >>= 1)
                acc += __shfl_down(acc, off);
            if (lane == 0) {
                acc += qbias(loadT(fb1, o, isbf), den);
                U[A4 + o] = qrelu(acc, sa4);
            }
        }
    }
    __syncthreads();

    if (tid < 96) {
        const int d = tid >> 4, g = tid & 15;
        const void* hw = (d < 4) ? bw : cw;
        const int row = (d < 4) ? d : d - 4;
        const float swh = (d < 4) ? swbs : swcs;
        float p = 0.f;
        #pragma unroll
        for (int k = 0; k < 8; ++k) {
            const int kk = g * 8 + k;
            p = fmaf(U[A4 + kk], quantw(loadT(hw, row * 128 + kk, isbf), swh), p);
        }
        U[PART + d * 16 + g] = p;
    }
    __syncthreads();
    if (tid < 6) {
        const int d = tid;
        float acc;
        if (d < 4) acc = qbias(loadT(bb, d, isbf), sa4 * swbs);
        else       acc = qbias(loadT(cb, d - 4, isbf), sa4 * swcs);
        for (int g = 0; g < 16; ++g) acc += U[PART + d * 16 + g];
        if (d < 4) outp[(size_t)b * 4 + d] = fminf(fmaxf(rintf(acc / sab), -8.f), 7.f) * sab;
        else outp[16384 + (size_t)b * 2 + (d - 4)] = fminf(fmaxf(rintf(acc / sac), -8.f), 7.f) * sac;
    }
}

extern "C" void kernel_launch(void* const* d_in, const int* in_sizes, int n_in,
                              void* d_out, int out_size, void* d_ws, size_t ws_size,
                              hipStream_t stream)
{
    float* out = (float*)d_out;
    const int expect[20] = { 7077888, 756, 28, 12096, 48, 12288, 64, 73728, 128,
                             512, 4, 256, 2, 1, 1, 1, 1, 1, 1, 1 };
    if (n_in < 20) { k_beacon<<<1, 64, 0, stream>>>(out, 9000.f); return; }
    for (int i = 0; i < 20; ++i)
        if (in_sizes[i] != expect[i]) {
            k_beacon<<<1, 64, 0, stream>>>(out, 2000.f + 10.f * i);
            return;
        }

    if (ws_size >= (size_t)100000 * sizeof(float)) {
        float* ws = (float*)d_ws;
        k_scale<<<35, 256, 0, stream>>>(
            d_in[1], d_in[3], d_in[5], d_in[7], d_in[9], d_in[11],
            d_in[13], d_in[14], d_in[15], d_in[16], d_in[17], d_in[18], d_in[19],
            ws);
        k_quant<<<34, 256, 0, stream>>>(
            d_in[1], d_in[2], d_in[3], d_in[4], d_in[5], d_in[6],
            d_in[7], d_in[8], d_in[9], d_in[10], d_in[11], d_in[12],
            ws);
        k_net<<<4096, 256, 0, stream>>>(d_in[0], ws, out);
    } else {
        k_net_fb<<<4096, 256, 0, stream>>>(
            d_in[0], d_in[1], d_in[2], d_in[3], d_in[4], d_in[5], d_in[6],
            d_in[7], d_in[8], d_in[9], d_in[10], d_in[11], d_in[12],
            d_in[13], d_in[14], d_in[15], d_in[16], d_in[17], d_in[18], d_in[19],
            out);
    }
}